// Round 8
// baseline (48.852 us; speedup 1.0000x reference)
//
#include <hip/hip_runtime.h>

#define WPTS 801
#define ROWS 4
#define NT 256

struct c2 { float x, y; };

__device__ __forceinline__ c2 c_addc(c2 a, c2 b) { return {a.x + b.x, a.y + b.y}; }
__device__ __forceinline__ c2 c_subc(c2 a, c2 b) { return {a.x - b.x, a.y - b.y}; }
__device__ __forceinline__ c2 c_divc(c2 a, c2 b) {
    float inv = 1.0f / (b.x * b.x + b.y * b.y);
    return {(a.x * b.x + a.y * b.y) * inv, (a.y * b.x - a.x * b.y) * inv};
}

__global__ __launch_bounds__(NT, 8)
void kla_tmm_kernel(const float* __restrict__ d_phys,
                    const float* __restrict__ nSi_f,
                    const float* __restrict__ nSiO2_f,
                    const float* __restrict__ nSi3N4_f,
                    const float* __restrict__ lam,
                    float* __restrict__ out,
                    int B)
{
    const int nRowBlks = (B + ROWS - 1) / ROWS;
    const int t = blockIdx.x * NT + threadIdx.x;
    if (t >= nRowBlks * WPTS) return;

    const int w = t % WPTS;
    const int row0 = (t / WPTS) * ROWS;
    const int nrows = min(ROWS, B - row0);

    // ---- Layout-robust complex reads (same detection as passing r2-r7) ----
    const bool ilv = (nSiO2_f[1] == 0.0f);
    float nSx, nSy, nOx, nOy, nNx, nNy;
    if (ilv) {
        nSx = nSi_f[2 * w];    nSy = nSi_f[2 * w + 1];
        nOx = nSiO2_f[2 * w];  nOy = nSiO2_f[2 * w + 1];
        nNx = nSi3N4_f[2 * w]; nNy = nSi3N4_f[2 * w + 1];
    } else {
        nSx = nSi_f[w];    nSy = 0.0f;
        nOx = nSiO2_f[w];  nOy = 0.0f;
        nNx = nSi3N4_f[w]; nNy = 0.0f;
    }

    const bool realn = (nOy == 0.0f) && (nNy == 0.0f) && (nSy == 0.0f);

    if (realn && nrows == ROWS) {
        // ==== real-n fast path, v-basis, hoisted float4 loads, dual chain ====
        const float rlam = __builtin_amdgcn_rcpf(lam[w]);
        const float kOr = nOx * rlam;                        // SiO2 : rev/nm
        const float kNr = nNx * rlam;                        // Si3N4: rev/nm
        const float gAO = __builtin_amdgcn_rcpf(nOx);        // Air |SiO2 : 1/nO
        const float gON = nOx * __builtin_amdgcn_rcpf(nNx);  // SiO2|Si3N4: nO/nN
        const float gNO = nNx * gAO;                         // Si3N4|SiO2: nN/nO

        // All 28 thicknesses of this thread's 4 rows: 7 aligned float4 loads.
        const float4* dv = (const float4*)(d_phys + (size_t)row0 * 7);
        float4 q0 = dv[0], q1 = dv[1], q2 = dv[2], q3 = dv[3],
               q4 = dv[4], q5 = dv[5], q6 = dv[6];
        float df[28];
        df[0]=q0.x; df[1]=q0.y; df[2]=q0.z; df[3]=q0.w;
        df[4]=q1.x; df[5]=q1.y; df[6]=q1.z; df[7]=q1.w;
        df[8]=q2.x; df[9]=q2.y; df[10]=q2.z; df[11]=q2.w;
        df[12]=q3.x; df[13]=q3.y; df[14]=q3.z; df[15]=q3.w;
        df[16]=q4.x; df[17]=q4.y; df[18]=q4.z; df[19]=q4.w;
        df[20]=q5.x; df[21]=q5.y; df[22]=q5.z; df[23]=q5.w;
        df[24]=q6.x; df[25]=q6.y; df[26]=q6.z; df[27]=q6.w;

        float* orow = out + (size_t)row0 * WPTS + w;

        #pragma unroll
        for (int pr = 0; pr < ROWS; pr += 2) {
            // chain A = row pr, chain B = row pr+1 (independent — ILP 2)
            float a0x = nOx, a0y = 0.0f, a1x = nSx, a1y = 0.0f;
            float b0x = nOx, b0y = 0.0f, b1x = nSx, b1y = 0.0f;

            #pragma unroll
            for (int i = 7; i >= 1; --i) {
                const float kk = (i & 1) ? kOr : kNr;
                const float g  = (i == 1) ? gAO : ((i & 1) ? gNO : gON);
                const float nuA = df[pr * 7 + (i - 1)] * kk;       // compile-time idx
                const float nuB = df[(pr + 1) * 7 + (i - 1)] * kk;
                const float sA = __builtin_amdgcn_sinf(nuA);  // sin(2*pi*nu)
                const float cA = __builtin_amdgcn_cosf(nuA);
                const float sB = __builtin_amdgcn_sinf(nuB);
                const float cB = __builtin_amdgcn_cosf(nuB);

                // phase mix: v0' = c v0 - i s v1 ; v1' = c v1 - i s v0
                const float wA0x = a0x * cA + a1y * sA;
                const float wA0y = a0y * cA - a1x * sA;
                const float wA1x = a1x * cA + a0y * sA;
                const float wA1y = a1y * cA - a0x * sA;
                const float wB0x = b0x * cB + b1y * sB;
                const float wB0y = b0y * cB - b1x * sB;
                const float wB1x = b1x * cB + b0y * sB;
                const float wB1y = b1y * cB - b0x * sB;
                // interface: v0 *= g (v1 factor folded into global scale)
                a0x = wA0x * g;  a0y = wA0y * g;  a1x = wA1x;  a1y = wA1y;
                b0x = wB0x * g;  b0y = wB0y * g;  b1x = wB1x;  b1y = wB1y;
            }

            // R = |v0-v1|^2 / |v0+v1|^2
            {
                const float ax = a0x - a1x, ay = a0y - a1y;
                const float bx = a0x + a1x, by = a0y + a1y;
                const float num = ax * ax + ay * ay;
                const float den = bx * bx + by * by;
                orow[(size_t)pr * WPTS] = num * __builtin_amdgcn_rcpf(den);
            }
            {
                const float ax = b0x - b1x, ay = b0y - b1y;
                const float bx = b0x + b1x, by = b0y + b1y;
                const float num = ax * ax + ay * ay;
                const float den = bx * bx + by * by;
                orow[(size_t)(pr + 1) * WPTS] = num * __builtin_amdgcn_rcpf(den);
            }
        }
    } else {
        // ======== general complex path (round-2 code, known correct) ========
        const float k0 = 6.28318530717958647692f / lam[w];
        const c2 nA = {1.0f, 0.0f};
        const c2 nO = {nOx, nOy}, nN = {nNx, nNy}, nS = {nSx, nSy};
        const c2 rAO  = c_divc(c_subc(nA, nO), c_addc(nA, nO));
        const c2 rON  = c_divc(c_subc(nO, nN), c_addc(nO, nN));
        const c2 rNO  = {-rON.x, -rON.y};
        const c2 rOSi = c_divc(c_subc(nO, nS), c_addc(nO, nS));
        const c2 kO = {k0 * nO.x, k0 * nO.y};
        const c2 kN = {k0 * nN.x, k0 * nN.y};

        for (int rr = 0; rr < nrows; ++rr) {
            const int row = row0 + rr;
            const float* dd = d_phys + (size_t)row * 7;

            c2 u0 = {1.0f, 0.0f};
            c2 u1 = rOSi;

            #pragma unroll
            for (int i = 7; i >= 1; --i) {
                const float d = dd[i - 1];
                const c2 kk = (i & 1) ? kO : kN;
                const float alpha = kk.x * d;
                const float beta  = kk.y * d;
                float s, c;
                __sincosf(alpha, &s, &c);
                const float ep = __expf(beta);
                const float em = __expf(-beta);

                c2 v;
                v.x = ep * (u0.x * c + u0.y * s);
                v.y = ep * (u0.y * c - u0.x * s);
                u0 = v;
                v.x = em * (u1.x * c - u1.y * s);
                v.y = em * (u1.y * c + u1.x * s);
                u1 = v;

                const c2 ri = (i == 1) ? rAO : ((i & 1) ? rNO : rON);
                c2 w0, w1;
                w0.x = u0.x + ri.x * u1.x - ri.y * u1.y;
                w0.y = u0.y + ri.x * u1.y + ri.y * u1.x;
                w1.x = u1.x + ri.x * u0.x - ri.y * u0.y;
                w1.y = u1.y + ri.x * u0.y + ri.y * u0.x;
                u0 = w0; u1 = w1;
            }

            out[(size_t)row * WPTS + w] =
                (u1.x * u1.x + u1.y * u1.y) / (u0.x * u0.x + u0.y * u0.y);
        }
    }
}

extern "C" void kernel_launch(void* const* d_in, const int* in_sizes, int n_in,
                              void* d_out, int out_size, void* d_ws, size_t ws_size,
                              hipStream_t stream) {
    const float* d_phys  = (const float*)d_in[0];
    const float* nSi     = (const float*)d_in[1];
    const float* nSiO2   = (const float*)d_in[2];
    const float* nSi3N4  = (const float*)d_in[3];
    const float* lam     = (const float*)d_in[4];
    float* out = (float*)d_out;

    const int B = in_sizes[0] / 7;
    const int nRowBlks = (B + ROWS - 1) / ROWS;
    const int nTasks = nRowBlks * WPTS;
    const int grid = (nTasks + NT - 1) / NT;

    kla_tmm_kernel<<<grid, NT, 0, stream>>>(
        d_phys, nSi, nSiO2, nSi3N4, lam, out, B);
}

// Round 9
// 46.293 us; speedup vs baseline: 1.0553x; 1.0553x over previous
//
#include <hip/hip_runtime.h>

#define WPTS 801
#define ROWS 4
#define NT 256

typedef _Float16 h2 __attribute__((ext_vector_type(2)));

struct c2 { float x, y; };

__device__ __forceinline__ c2 c_addc(c2 a, c2 b) { return {a.x + b.x, a.y + b.y}; }
__device__ __forceinline__ c2 c_subc(c2 a, c2 b) { return {a.x - b.x, a.y - b.y}; }
__device__ __forceinline__ c2 c_divc(c2 a, c2 b) {
    float inv = 1.0f / (b.x * b.x + b.y * b.y);
    return {(a.x * b.x + a.y * b.y) * inv, (a.y * b.x - a.x * b.y) * inv};
}

__device__ __forceinline__ h2 h2bcast(float v) {
    h2 r; r.x = (_Float16)v; r.y = (_Float16)v; return r;
}

__global__ __launch_bounds__(NT)
void kla_tmm_kernel(const float* __restrict__ d_phys,
                    const float* __restrict__ nSi_f,
                    const float* __restrict__ nSiO2_f,
                    const float* __restrict__ nSi3N4_f,
                    const float* __restrict__ lam,
                    float* __restrict__ out,
                    int B)
{
    const int nRowBlks = (B + ROWS - 1) / ROWS;
    const int t = blockIdx.x * NT + threadIdx.x;
    if (t >= nRowBlks * WPTS) return;

    const int w = t % WPTS;
    const int row0 = (t / WPTS) * ROWS;
    const int nrows = min(ROWS, B - row0);

    // ---- Layout-robust complex reads (same detection as passing r2-r8) ----
    const bool ilv = (nSiO2_f[1] == 0.0f);
    float nSx, nSy, nOx, nOy, nNx, nNy;
    if (ilv) {
        nSx = nSi_f[2 * w];    nSy = nSi_f[2 * w + 1];
        nOx = nSiO2_f[2 * w];  nOy = nSiO2_f[2 * w + 1];
        nNx = nSi3N4_f[2 * w]; nNy = nSi3N4_f[2 * w + 1];
    } else {
        nSx = nSi_f[w];    nSy = 0.0f;
        nOx = nSiO2_f[w];  nOy = 0.0f;
        nNx = nSi3N4_f[w]; nNy = 0.0f;
    }

    const bool realn = (nOy == 0.0f) && (nNy == 0.0f) && (nSy == 0.0f);

    if (realn && nrows == ROWS) {
        // ==== real-n fast path: v-basis, phase-reduce in f32, poly+mix in f16x2 ====
        // nu in HALF-revolutions: angle = pi * nu. t = nu - rint(nu) in [-1/2,1/2];
        // the (-1)^m parity flips (s,c) jointly -> scales (v0,v1) by -1 -> cancels in R.
        const float rlam = __builtin_amdgcn_rcpf(lam[w]);
        const float kO2 = 2.0f * nOx * rlam;
        const float kN2 = 2.0f * nNx * rlam;
        const float gAO = __builtin_amdgcn_rcpf(nOx);        // Air |SiO2 : 1/nO
        const float gON = nOx * __builtin_amdgcn_rcpf(nNx);  // SiO2|Si3N4: nO/nN
        const float gNO = nNx * gAO;                         // Si3N4|SiO2: nN/nO

        const h2 hgAO = h2bcast(gAO);
        const h2 hgON = h2bcast(gON);
        const h2 hgNO = h2bcast(gNO);

        // sin(pi t) deg-7 Taylor (abs err 1.6e-4), cos(pi t) deg-6 (abs err 9.2e-4)
        const h2 hA1 = h2bcast( 3.14159265f);
        const h2 hA3 = h2bcast(-5.16771278f);
        const h2 hA5 = h2bcast( 2.55016404f);
        const h2 hA7 = h2bcast(-0.59926453f);
        const h2 hC2 = h2bcast(-4.93480220f);
        const h2 hC4 = h2bcast( 4.05871213f);
        const h2 hC6 = h2bcast(-1.33526277f);
        const h2 hOne = h2bcast(1.0f);

        const h2 v0init = h2bcast(nOx);
        const h2 v1init = h2bcast(nSx);

        const float* base = d_phys + (size_t)row0 * 7;
        float* orow = out + (size_t)row0 * WPTS + w;

        #pragma unroll
        for (int pr = 0; pr < ROWS; pr += 2) {
            const float* dA = base + (size_t)pr * 7;
            const float* dB = dA + 7;

            h2 v0x = v0init, v0y = h2bcast(0.0f);
            h2 v1x = v1init, v1y = h2bcast(0.0f);

            #pragma unroll
            for (int i = 7; i >= 1; --i) {
                const float kk = (i & 1) ? kO2 : kN2;
                const h2 hg = (i == 1) ? hgAO : ((i & 1) ? hgNO : hgON);

                const float nuA = dA[i - 1] * kk;
                const float nuB = dB[i - 1] * kk;
                const float tA = nuA - __builtin_rintf(nuA);
                const float tB = nuB - __builtin_rintf(nuB);
                h2 tt; tt.x = (_Float16)tA; tt.y = (_Float16)tB;

                h2 q = tt * tt;
                h2 ps = hA5 + q * hA7;
                ps = hA3 + q * ps;
                ps = hA1 + q * ps;
                h2 s = tt * ps;                 // sin(pi t) (up to joint sign)
                h2 pc = hC4 + q * hC6;
                pc = hC2 + q * pc;
                h2 c = hOne + q * pc;           // cos(pi t)

                h2 gc = hg * c;
                h2 gs = hg * s;
                // v0' = g*(c v0 - i s v1) ; v1' = c v1 - i s v0
                h2 nv0x = gc * v0x + gs * v1y;
                h2 nv0y = gc * v0y - gs * v1x;
                h2 nv1x = c * v1x + s * v0y;
                h2 nv1y = c * v1y - s * v0x;
                v0x = nv0x; v0y = nv0y; v1x = nv1x; v1y = nv1y;
            }

            // Epilogue in f32: R = |v0-v1|^2 / |v0+v1|^2
            {
                const float p0x = (float)v0x.x, p0y = (float)v0y.x;
                const float p1x = (float)v1x.x, p1y = (float)v1y.x;
                const float ax = p0x - p1x, ay = p0y - p1y;
                const float bx = p0x + p1x, by = p0y + p1y;
                const float num = ax * ax + ay * ay;
                const float den = bx * bx + by * by;
                orow[(size_t)pr * WPTS] = num * __builtin_amdgcn_rcpf(den);
            }
            {
                const float p0x = (float)v0x.y, p0y = (float)v0y.y;
                const float p1x = (float)v1x.y, p1y = (float)v1y.y;
                const float ax = p0x - p1x, ay = p0y - p1y;
                const float bx = p0x + p1x, by = p0y + p1y;
                const float num = ax * ax + ay * ay;
                const float den = bx * bx + by * by;
                orow[(size_t)(pr + 1) * WPTS] = num * __builtin_amdgcn_rcpf(den);
            }
        }
    } else {
        // ======== general complex path (round-2 code, known correct) ========
        const float k0 = 6.28318530717958647692f / lam[w];
        const c2 nA = {1.0f, 0.0f};
        const c2 nO = {nOx, nOy}, nN = {nNx, nNy}, nS = {nSx, nSy};
        const c2 rAO  = c_divc(c_subc(nA, nO), c_addc(nA, nO));
        const c2 rON  = c_divc(c_subc(nO, nN), c_addc(nO, nN));
        const c2 rNO  = {-rON.x, -rON.y};
        const c2 rOSi = c_divc(c_subc(nO, nS), c_addc(nO, nS));
        const c2 kO = {k0 * nO.x, k0 * nO.y};
        const c2 kN = {k0 * nN.x, k0 * nN.y};

        for (int rr = 0; rr < nrows; ++rr) {
            const int row = row0 + rr;
            const float* dd = d_phys + (size_t)row * 7;

            c2 u0 = {1.0f, 0.0f};
            c2 u1 = rOSi;

            #pragma unroll
            for (int i = 7; i >= 1; --i) {
                const float d = dd[i - 1];
                const c2 kk = (i & 1) ? kO : kN;
                const float alpha = kk.x * d;
                const float beta  = kk.y * d;
                float s, c;
                __sincosf(alpha, &s, &c);
                const float ep = __expf(beta);
                const float em = __expf(-beta);

                c2 v;
                v.x = ep * (u0.x * c + u0.y * s);
                v.y = ep * (u0.y * c - u0.x * s);
                u0 = v;
                v.x = em * (u1.x * c - u1.y * s);
                v.y = em * (u1.y * c + u1.x * s);
                u1 = v;

                const c2 ri = (i == 1) ? rAO : ((i & 1) ? rNO : rON);
                c2 w0, w1;
                w0.x = u0.x + ri.x * u1.x - ri.y * u1.y;
                w0.y = u0.y + ri.x * u1.y + ri.y * u1.x;
                w1.x = u1.x + ri.x * u0.x - ri.y * u0.y;
                w1.y = u1.y + ri.x * u0.y + ri.y * u0.x;
                u0 = w0; u1 = w1;
            }

            out[(size_t)row * WPTS + w] =
                (u1.x * u1.x + u1.y * u1.y) / (u0.x * u0.x + u0.y * u0.y);
        }
    }
}

extern "C" void kernel_launch(void* const* d_in, const int* in_sizes, int n_in,
                              void* d_out, int out_size, void* d_ws, size_t ws_size,
                              hipStream_t stream) {
    const float* d_phys  = (const float*)d_in[0];
    const float* nSi     = (const float*)d_in[1];
    const float* nSiO2   = (const float*)d_in[2];
    const float* nSi3N4  = (const float*)d_in[3];
    const float* lam     = (const float*)d_in[4];
    float* out = (float*)d_out;

    const int B = in_sizes[0] / 7;
    const int nRowBlks = (B + ROWS - 1) / ROWS;
    const int nTasks = nRowBlks * WPTS;
    const int grid = (nTasks + NT - 1) / NT;

    kla_tmm_kernel<<<grid, NT, 0, stream>>>(
        d_phys, nSi, nSiO2, nSi3N4, lam, out, B);
}